// Round 11
// baseline (125.757 us; speedup 1.0000x reference)
//
#include <hip/hip_runtime.h>
#include <hip/hip_bf16.h>

#define EPSF 1e-15f
#define MAXNF 0.99999f

typedef __attribute__((ext_vector_type(8))) short short8v;
typedef __attribute__((ext_vector_type(8))) ushort ushort8v;
typedef __attribute__((ext_vector_type(4))) float f32x4;

__device__ __forceinline__ float wave_sum(float v) {
#pragma unroll
    for (int off = 32; off > 0; off >>= 1) v += __shfl_xor(v, off, 64);
    return v;
}
__device__ __forceinline__ float rcpf(float x) { return __builtin_amdgcn_rcpf(x); }
// x >= 0; series guard avoids (1-e) cancellation at small x (branchy: wave-uniform x)
__device__ __forceinline__ float tanh_g(float x) {
    if (x < 0.03f) return x * (1.f - 0.33333333f * x * x);
    float e = __expf(-2.f * x);
    return (1.f - e) * rcpf(1.f + e);
}
__device__ __forceinline__ float atanh_g(float x) {
    if (x < 0.03f) return x * (1.f + 0.33333333f * x * x);
    return 0.5f * __logf((1.f + x) * rcpf(1.f - x));
}
// branchless variants for lane-divergent inputs
__device__ __forceinline__ float tanh_b(float x) {
    float e = __expf(-2.f * x);
    float tv = (1.f - e) * rcpf(1.f + e);
    float sv = x * (1.f - 0.33333333f * x * x);
    return (x < 0.03f) ? sv : tv;
}
__device__ __forceinline__ float atanh_b(float x) {
    float lv = 0.5f * __logf((1.f + x) * rcpf(1.f - x));
    float sv = x * (1.f + 0.33333333f * x * x);
    return (x < 0.03f) ? sv : lv;
}
__device__ __forceinline__ ushort f2bf(float f) {
    uint32_t u = __float_as_uint(f);
    uint32_t r = (u + 0x7fffu + ((u >> 16) & 1u)) >> 16;
    return (ushort)r;
}
__device__ __forceinline__ float bf2f(ushort u) { return __uint_as_float(((uint32_t)u) << 16); }

// ---------------- K0: prep — W1^T/W2^T bf16, W_vel hi/lo, W_enc^T hi/lo, c = expmap0(b_vel) ----------------
__global__ __launch_bounds__(256) void k_prep(
    const float* __restrict__ W1, const float* __restrict__ W2,
    const float* __restrict__ W_vel, const float* __restrict__ b_vel,
    const float* __restrict__ W_enc,
    ushort* __restrict__ W1t, ushort* __restrict__ W2tp,
    ushort* __restrict__ Wvh, ushort* __restrict__ Wvl,
    ushort* __restrict__ Weth, ushort* __restrict__ Wetl,
    float* __restrict__ cvec, float* __restrict__ scp) {
    int bid = blockIdx.x, tid = threadIdx.x;
    if (bid == 0) {
        __shared__ float red[4];
        float v = (tid < 128) ? b_vel[tid] : 0.f;
        float p = wave_sum(v * v);
        if ((tid & 63) == 0) red[tid >> 6] = p;
        __syncthreads();
        float ssq = red[0] + red[1] + red[2] + red[3];
        float nn = sqrtf(fmaxf(ssq, EPSF));
        float th = tanhf(nn);
        if (tid < 128) cvec[tid] = th / nn * v;
        if (tid == 0) scp[0] = th * th;
    } else if (bid <= 128) {
        int idx = (bid - 1) * 256 + tid;      // n*128 + k
        int n = idx >> 7, k = idx & 127;
        W1t[idx] = f2bf(W1[k * 256 + n]);
    } else if (bid <= 160) {
        int idx = (bid - 129) * 256 + tid;    // s*256 + j  (s padded to 32)
        int s = idx >> 8, j = idx & 255;
        W2tp[idx] = (s < 24) ? f2bf(W2[j * 24 + s]) : (ushort)0;
    } else if (bid <= 224) {
        int idx = (bid - 161) * 256 + tid;    // j*128 + k
        float wv = W_vel[idx];
        ushort h = f2bf(wv);
        Wvh[idx] = h;
        Wvl[idx] = f2bf(wv - bf2f(h));
    } else {
        int idx = (bid - 225) * 256 + tid;    // d*32 + s (s padded to 32)
        int d = idx >> 5, s = idx & 31;
        float wv = (s < 24) ? W_enc[s * 128 + d] : 0.f;
        ushort h = f2bf(wv);
        Weth[idx] = h;
        Wetl[idx] = f2bf(wv - bf2f(h));
    }
}

// ---------------- K1: RevIN stats -> norm + denorm coeffs (32 f per block) ----------------
__global__ __launch_bounds__(256) void k_stats(
    const float* __restrict__ x, const float* __restrict__ revin_w, const float* __restrict__ revin_b,
    float* __restrict__ sc_o, float* __restrict__ sh_o,
    float* __restrict__ osc_o, float* __restrict__ osh_o) {
    __shared__ float ps[8][32], ps2[8][32];
    int b = blockIdx.x >> 2, fg = blockIdx.x & 3, tid = threadIdx.x;
    int f = fg * 32 + (tid & 31), sl = tid >> 5;   // 8 L-slices of 42
    const float* xp = x + ((size_t)b * 336 + sl * 42) * 128 + f;
    float s = 0.f, s2 = 0.f;
    for (int l = 0; l < 42; ++l) { float v = xp[(size_t)l * 128]; s += v; s2 += v * v; }
    ps[sl][tid & 31] = s; ps2[sl][tid & 31] = s2;
    __syncthreads();
    if (tid < 32) {
        float S = 0.f, S2 = 0.f;
#pragma unroll
        for (int h = 0; h < 8; ++h) { S += ps[h][tid]; S2 += ps2[h][tid]; }
        float m = S * (1.f / 336.f);
        float var = S2 * (1.f / 336.f) - m * m;
        float sd = sqrtf(var + 1e-5f);
        int ff = fg * 32 + tid;
        int r = b * 128 + ff;
        float rw = revin_w[ff], rb = revin_b[ff];
        float sc = rw * rcpf(sd);
        sc_o[r] = sc;
        sh_o[r] = rb - m * sc;
        float oc = sd * rcpf(rw);
        osc_o[r] = oc;
        osh_o[r] = m - rb * oc;
    }
}

// ---------------- K2: u = xn_seg @ W_enc + b_enc via MFMA (bf16 hi/lo ~ fp32), out bf16 ----------------
__global__ __launch_bounds__(256) void k_u(
    const float* __restrict__ x, const float* __restrict__ sc_i, const float* __restrict__ sh_i,
    const ushort* __restrict__ Weth, const ushort* __restrict__ Wetl,
    const float* __restrict__ b_enc,
    ushort* __restrict__ ub) {
    __shared__ __align__(16) ushort xsT[128][72];   // [f][0..31 hi | 40..71 lo], 18.4KB
    int bid = blockIdx.x;
    int b = bid / 14, n = bid - b * 14;
    int tid = threadIdx.x;
    {
        int f = tid & 127, sh2 = tid >> 7;
        float scf = sc_i[b * 128 + f], shf = sh_i[b * 128 + f];
        const float* xp = x + ((size_t)b * 336 + n * 24) * 128 + f;
#pragma unroll
        for (int s2 = 0; s2 < 12; ++s2) {
            int s = s2 * 2 + sh2;
            float v = xp[(size_t)s * 128] * scf + shf;
            ushort h = f2bf(v);
            xsT[f][s] = h;
            xsT[f][40 + s] = f2bf(v - bf2f(h));
        }
#pragma unroll
        for (int q = 0; q < 4; ++q) {   // zero K-padding s=24..31 (hi) and 64..71 (lo)
            xsT[f][24 + sh2 * 4 + q] = 0;
            xsT[f][64 + sh2 * 4 + q] = 0;
        }
    }
    __syncthreads();
    int wid = tid >> 6, lane = tid & 63;
    int lrow = lane & 15, lk = lane >> 4;
    short8v Bh[2], Bl[2];
#pragma unroll
    for (int dt = 0; dt < 2; ++dt) {
        int d = (wid * 2 + dt) * 16 + lrow;
        Bh[dt] = *(const short8v*)(Weth + d * 32 + lk * 8);
        Bl[dt] = *(const short8v*)(Wetl + d * 32 + lk * 8);
    }
    float be[2];
#pragma unroll
    for (int dt = 0; dt < 2; ++dt) be[dt] = b_enc[(wid * 2 + dt) * 16 + lrow];
#pragma unroll
    for (int ft = 0; ft < 8; ++ft) {
        int fr = ft * 16 + lrow;
        short8v Ah = *(const short8v*)&xsT[fr][lk * 8];
        short8v Al = *(const short8v*)&xsT[fr][40 + lk * 8];
#pragma unroll
        for (int dt = 0; dt < 2; ++dt) {
            f32x4 acc = (f32x4)(0.f);
            acc = __builtin_amdgcn_mfma_f32_16x16x32_bf16(Ah, Bh[dt], acc, 0, 0, 0);
            acc = __builtin_amdgcn_mfma_f32_16x16x32_bf16(Ah, Bl[dt], acc, 0, 0, 0);
            acc = __builtin_amdgcn_mfma_f32_16x16x32_bf16(Al, Bh[dt], acc, 0, 0, 0);
            int d = (wid * 2 + dt) * 16 + lrow;
#pragma unroll
            for (int j = 0; j < 4; ++j) {
                int f = ft * 16 + lk * 4 + j;
                ub[((size_t)(b * 128 + f) * 14 + n) * 128 + d] = f2bf(acc[j] + be[dt]);
            }
        }
    }
}

// ---------------- K3: hyperbolic recurrence — MFMA Gram + lane-parallel scalar recurrence ----------------
__global__ __launch_bounds__(256, 2) void k_encode(
    const ushort* __restrict__ ub,
    float* __restrict__ z0_o, float* __restrict__ vinit_o) {
    __shared__ float gram[32][29];
    __shared__ float coef[32][17];
    int tid = threadIdx.x;
    int w = tid >> 6, lane = tid & 63;
    int lrow = lane & 15, lk = lane >> 4;
    int rbase = blockIdx.x * 32;

    for (int i = 0; i < 8; i += 2) {
        int rl0 = w * 8 + i, rl1 = rl0 + 1;
        const ushort* t0 = ub + (size_t)(rbase + rl0) * 1792 + lrow * 128 + lk * 8;
        const ushort* t1 = t0 + 1792;
        short8v a0[4], a1[4];
#pragma unroll
        for (int kk = 0; kk < 4; ++kk) {
            a0[kk] = *(const short8v*)(t0 + kk * 32);
            a1[kk] = *(const short8v*)(t1 + kk * 32);
        }
        f32x4 g0 = (f32x4)(0.f), g1 = (f32x4)(0.f);
#pragma unroll
        for (int kk = 0; kk < 4; ++kk) {
            g0 = __builtin_amdgcn_mfma_f32_16x16x32_bf16(a0[kk], a0[kk], g0, 0, 0, 0);
            g1 = __builtin_amdgcn_mfma_f32_16x16x32_bf16(a1[kk], a1[kk], g1, 0, 0, 0);
        }
#pragma unroll
        for (int j = 0; j < 4; ++j) {
            int crow = lk * 4 + j, ccol = lrow;
            if (crow == ccol && crow < 14) { gram[rl0][crow] = g0[j]; gram[rl1][crow] = g1[j]; }
            if (crow + 1 == ccol && ccol < 14) { gram[rl0][14 + ccol] = g0[j]; gram[rl1][14 + ccol] = g1[j]; }
        }
    }
    __syncthreads();

    if (tid < 32) {
        float wsum = 0.f;
        { float p = 1.f; for (int k = 0; k < 13; ++k) { wsum += p; p *= 0.9f; } }
        float wi; { float p = 1.f; for (int k = 0; k < 12; ++k) p *= 0.9f; wi = p / (wsum * 13.f); }
        float c[14];
#pragma unroll
        for (int m = 0; m < 14; ++m) c[m] = 0.f;
        float sczp = 0.f, szp = 0.f;
#pragma unroll
        for (int n = 0; n < 14; ++n) {
            float ssq = gram[tid][n];
            float nn = sqrtf(fmaxf(ssq, EPSF));
            float th = tanh_g(nn);
            float scz, sz;
            if (th > MAXNF) { scz = MAXNF * rcpf(nn); sz = MAXNF * MAXNF; }
            else            { scz = th * rcpf(nn);    sz = th * th; }
            if (n > 0) {
                float dotup = gram[tid][14 + n];
                float xyp = sczp * scz * dotup;
                float t2 = 1.f - 2.f * xyp;
                float den = fmaxf(t2 + szp * sz, EPSF);
                float rden = rcpf(den);
                float a1 = t2 + sz, a2 = 1.f - szp;
                float usq = (a1 * a1 * szp - 2.f * a1 * a2 * xyp + a2 * a2 * sz) * (rden * rden);
                float un = sqrtf(fmaxf(usq, EPSF));
                float art = atanh_g(fminf(un, 1.f - 1e-7f));
                float fac = fmaxf(a2, EPSF) * art * rcpf(un) * rden * wi;
                c[n - 1] += -fac * a1 * sczp;
                c[n]     +=  fac * a2 * scz;
                wi *= (1.f / 0.9f);
            }
            sczp = scz; szp = sz;
        }
#pragma unroll
        for (int m = 0; m < 14; ++m) coef[tid][m] = c[m];
        coef[tid][14] = sczp;
    }
    __syncthreads();

    for (int i = 0; i < 8; ++i) {
        int rl = w * 8 + i;
        int r = rbase + rl;
        float cc[15];
#pragma unroll
        for (int m = 0; m < 15; ++m) cc[m] = coef[rl][m];
        const uint* up32 = (const uint*)(ub + (size_t)r * 1792);
        float v0 = 0.f, v1 = 0.f, za = 0.f, zb = 0.f;
#pragma unroll
        for (int n = 0; n < 14; ++n) {
            uint u = up32[n * 64 + lane];
            float x0 = __uint_as_float(u << 16);
            float x1 = __uint_as_float(u & 0xffff0000u);
            v0 += cc[n] * x0; v1 += cc[n] * x1;
            if (n == 13) { za = cc[14] * x0; zb = cc[14] * x1; }
        }
        size_t ob = (size_t)r * 128 + lane * 2;
        *(float2*)&vinit_o[ob] = make_float2(v0, v1);
        *(float2*)&z0_o[ob] = make_float2(za, zb);
    }
}

// ---------------- K4: mx = vinit @ W_vel^T via MFMA (bf16 hi/lo split ~ fp32) ----------------
__global__ __launch_bounds__(256) void k_mv(
    const float* __restrict__ vinit,
    const ushort* __restrict__ Wvh, const ushort* __restrict__ Wvl,
    float* __restrict__ mx_o) {
    int wid = threadIdx.x >> 6, lane = threadIdx.x & 63;
    int lrow = lane & 15, lk = lane >> 4;
    int r0 = blockIdx.x * 32;
    short8v Bh[2][4], Bl[2][4];
#pragma unroll
    for (int nt = 0; nt < 2; ++nt) {
        const ushort* wph = Wvh + (size_t)((wid * 2 + nt) * 16 + lrow) * 128 + lk * 8;
        const ushort* wpl = Wvl + (size_t)((wid * 2 + nt) * 16 + lrow) * 128 + lk * 8;
#pragma unroll
        for (int kk = 0; kk < 4; ++kk) {
            Bh[nt][kk] = *(const short8v*)(wph + kk * 32);
            Bl[nt][kk] = *(const short8v*)(wpl + kk * 32);
        }
    }
    f32x4 acc[2][2];
#pragma unroll
    for (int rg = 0; rg < 2; ++rg) { acc[rg][0] = (f32x4)(0.f); acc[rg][1] = (f32x4)(0.f); }
#pragma unroll
    for (int rg = 0; rg < 2; ++rg) {
#pragma unroll
        for (int kk = 0; kk < 4; ++kk) {
            const float* ap = vinit + (size_t)(r0 + rg * 16 + lrow) * 128 + kk * 32 + lk * 8;
            f32x4 a0 = *(const f32x4*)ap;
            f32x4 a1 = *(const f32x4*)(ap + 4);
            short8v Ah, Al;
#pragma unroll
            for (int i = 0; i < 8; ++i) {
                float xv = (i < 4) ? a0[i] : a1[i - 4];
                ushort h = f2bf(xv);
                Ah[i] = (short)h;
                Al[i] = (short)f2bf(xv - bf2f(h));
            }
#pragma unroll
            for (int nt = 0; nt < 2; ++nt) {
                acc[rg][nt] = __builtin_amdgcn_mfma_f32_16x16x32_bf16(Ah, Bh[nt][kk], acc[rg][nt], 0, 0, 0);
                acc[rg][nt] = __builtin_amdgcn_mfma_f32_16x16x32_bf16(Ah, Bl[nt][kk], acc[rg][nt], 0, 0, 0);
                acc[rg][nt] = __builtin_amdgcn_mfma_f32_16x16x32_bf16(Al, Bh[nt][kk], acc[rg][nt], 0, 0, 0);
            }
        }
    }
#pragma unroll
    for (int rg = 0; rg < 2; ++rg)
#pragma unroll
        for (int nt = 0; nt < 2; ++nt)
#pragma unroll
            for (int j = 0; j < 4; ++j)
                mx_o[(size_t)(r0 + rg * 16 + lk * 4 + j) * 128 + (wid * 2 + nt) * 16 + lrow] = acc[rg][nt][j];
}

// ---------------- K5: v0t tail + futures -> tan (bf16); f-major layout R=b*1024+t*128+f ----------------
__global__ __launch_bounds__(256) void k_future(
    const float* __restrict__ z0_i, const float* __restrict__ vinit, const float* __restrict__ mx_i,
    const float* __restrict__ cvec, const float* __restrict__ scp,
    const float* __restrict__ step_sizes, ushort* __restrict__ tanb) {
    int wid = threadIdx.x >> 6, lane = threadIdx.x & 63;
    int r = blockIdx.x * 4 + wid;
    size_t base = (size_t)r * 128 + lane * 2;
    float2 vi = *(const float2*)&vinit[base];
    float2 mx = *(const float2*)&mx_i[base];
    float2 z0 = *(const float2*)&z0_i[base];
    float2 cv = *(const float2*)&cvec[lane * 2];
    float scc = scp[0];
    float xn2  = wave_sum(vi.x * vi.x + vi.y * vi.y);
    float mxn2 = wave_sum(mx.x * mx.x + mx.y * mx.y);
    float mxc  = wave_sum(mx.x * cv.x + mx.y * cv.y);
    float z0mx = wave_sum(z0.x * mx.x + z0.y * mx.y);
    float z0c  = wave_sum(z0.x * cv.x + z0.y * cv.y);
    float x2   = wave_sum(z0.x * z0.x + z0.y * z0.y);
    float xn = sqrtf(fmaxf(xn2, EPSF));
    float mxn = sqrtf(fmaxf(mxn2, EPSF));
    float artx = atanh_g(fminf(xn, 1.f - 1e-7f));
    float tm = tanh_g(mxn * rcpf(xn) * artx);
    float scm = tm * rcpf(mxn);
    float sm = tm * tm;
    float xy2 = scm * mxc;
    float den2 = fmaxf(1.f + 2.f * xy2 + sm * scc, EPSF);
    float rd2 = rcpf(den2);
    float A2 = (1.f + 2.f * xy2 + scc) * scm * rd2;
    float B2 = (1.f - sm) * rd2;
    float v0n2 = A2 * A2 * mxn2 + 2.f * A2 * B2 * mxc + B2 * B2 * scc;
    float nv0 = sqrtf(fmaxf(v0n2, EPSF));
    if (nv0 > MAXNF) { float pf = MAXNF * rcpf(nv0); A2 *= pf; B2 *= pf; nv0 = MAXNF; }
    v0n2 = nv0 * nv0;
    float inv_nv0 = rcpf(nv0);
    float zdv = A2 * z0mx + B2 * z0c;
    float v00 = A2 * mx.x + B2 * cv.x, v01 = A2 * mx.y + B2 * cv.y;
    float il = rcpf(fmaxf(1.f - x2, EPSF));
    float step = rcpf(1.f + __expf(-step_sizes[0]));
    float tl = (float)((lane & 7) + 1);
    float nt_ = step * tl * nv0;
    float th = tanh_b(nt_ * il);
    float xy = th * inv_nv0 * zdv;
    float y2 = th * th;
    float den = fmaxf(1.f + 2.f * xy + x2 * y2, EPSF);
    float rd = rcpf(den);
    float A = (1.f + 2.f * xy + y2) * rd;
    float B = (1.f - x2) * th * inv_nv0 * rd;
    float rsq = A * A * x2 + 2.f * A * B * zdv + B * B * v0n2;
    float nr = sqrtf(fmaxf(rsq, EPSF));
    float pf2 = (nr > MAXNF) ? MAXNF * rcpf(nr) : 1.f;
    A *= pf2; B *= pf2; nr = fminf(nr, MAXNF);
    float art = atanh_b(fminf(nr, 1.f - 1e-7f));
    float tf = art * rcpf(nr);
    float FA = tf * A, FB = tf * B;
    uint* t32 = (uint*)tanb;
    int bb = r >> 7, f = r & 127;
#pragma unroll
    for (int t = 0; t < 8; ++t) {
        float FAt = __shfl(FA, t);
        float FBt = __shfl(FB, t);
        uint pk = (uint)f2bf(FAt * z0.x + FBt * v00) | ((uint)f2bf(FAt * z0.y + FBt * v01) << 16);
        t32[((size_t)(bb * 1024 + t * 128 + f)) * 64 + lane] = pk;
    }
}

// ---------------- K6: head — 1 tile/block (grid 2048), N-split B-resident waves, f-major epilogue ----------------
// Tile = 64 rows = one (b, t, f-half). Wave w owns GEMM1 cols [w*64,w*64+64).
__global__ __launch_bounds__(256, 2) void k_head(
    const ushort* __restrict__ tanb, const ushort* __restrict__ W1t, const float* __restrict__ b1,
    const ushort* __restrict__ W2tp, const float* __restrict__ b2,
    const float* __restrict__ osc_i, const float* __restrict__ osh_i,
    float* __restrict__ out) {
    __shared__ __align__(16) ushort hs[64][264];   // 33.8 KB; front 6.5 KB reused as ep[24][68] floats
    int tid = threadIdx.x;
    int wid = tid >> 6, lane = tid & 63;
    int lrow = lane & 15, lk = lane >> 4;
    int tile = blockIdx.x;

    // GEMM1 B-frags (L2-hot; 4 blocks/CU TLP hides the load latency)
    short8v Bw[4][4];
#pragma unroll
    for (int nt = 0; nt < 4; ++nt) {
        const ushort* wp = W1t + (size_t)((wid * 4 + nt) * 16 + lrow) * 128 + lk * 8;
#pragma unroll
        for (int kk = 0; kk < 4; ++kk) Bw[nt][kk] = *(const short8v*)(wp + kk * 32);
    }
    float b1v[4];
#pragma unroll
    for (int nt = 0; nt < 4; ++nt) b1v[nt] = b1[(wid * 4 + nt) * 16 + lrow];
    float b2a = (lrow < 24) ? b2[lrow] : 0.f;
    float b2bv = (lrow < 8) ? b2[16 + lrow] : 0.f;

    // A-frags for this tile
    short8v A[4][4];
    {
        const ushort* tp = tanb + ((size_t)tile * 64 + lrow) * 128 + lk * 8;
#pragma unroll
        for (int rg = 0; rg < 4; ++rg)
#pragma unroll
            for (int kk = 0; kk < 4; ++kk)
                A[rg][kk] = *(const short8v*)(tp + (size_t)rg * 2048 + kk * 32);
    }
    f32x4 acc[4][4];
#pragma unroll
    for (int rg = 0; rg < 4; ++rg)
#pragma unroll
        for (int nt = 0; nt < 4; ++nt) acc[rg][nt] = (f32x4)(0.f);
#pragma unroll
    for (int kk = 0; kk < 4; ++kk)
#pragma unroll
        for (int rg = 0; rg < 4; ++rg)
#pragma unroll
            for (int nt = 0; nt < 4; ++nt)
                acc[rg][nt] = __builtin_amdgcn_mfma_f32_16x16x32_bf16(A[rg][kk], Bw[nt][kk], acc[rg][nt], 0, 0, 0);
#pragma unroll
    for (int rg = 0; rg < 4; ++rg)
#pragma unroll
        for (int nt = 0; nt < 4; ++nt)
#pragma unroll
            for (int j = 0; j < 4; ++j)
                hs[rg * 16 + lk * 4 + j][(wid * 4 + nt) * 16 + lrow] =
                    f2bf(fmaxf(acc[rg][nt][j] + b1v[nt], 0.f));
    __syncthreads();
    // GEMM2: wave computes its 16 rows over full K=256
    f32x4 acc2[2];
    acc2[0] = (f32x4)(0.f); acc2[1] = (f32x4)(0.f);
#pragma unroll
    for (int kk2 = 0; kk2 < 8; ++kk2) {
        short8v Ah = *(const short8v*)&hs[wid * 16 + lrow][kk2 * 32 + lk * 8];
#pragma unroll
        for (int nt2 = 0; nt2 < 2; ++nt2) {
            short8v Bv = *(const short8v*)(W2tp + (size_t)(nt2 * 16 + lrow) * 256 + kk2 * 32 + lk * 8);
            acc2[nt2] = __builtin_amdgcn_mfma_f32_16x16x32_bf16(Ah, Bv, acc2[nt2], 0, 0, 0);
        }
    }
    __syncthreads();   // all hs reads done; safe to reuse as ep
    float* ep = (float*)&hs[0][0];   // [24][68]
#pragma unroll
    for (int nt2 = 0; nt2 < 2; ++nt2) {
        int col = nt2 * 16 + lrow;
        if (col < 24) {
            float bb2 = (nt2 == 0) ? b2a : b2bv;
#pragma unroll
            for (int j = 0; j < 4; ++j)
                ep[col * 68 + wid * 16 + lk * 4 + j] = acc2[nt2][j] + bb2;
        }
    }
    __syncthreads();
    // coalesced store: 384 float4; per (b,t,col) a 256B contiguous f-run
    int bb = tile >> 4, rem = tile & 15, tt = rem >> 1, f0 = (rem & 1) << 6;
#pragma unroll
    for (int pass = 0; pass < 2; ++pass) {
        int id = pass * 256 + tid;
        if (id < 384) {
            int col = id >> 4, c4 = id & 15;
            f32x4 v = *(f32x4*)&ep[col * 68 + c4 * 4];
            f32x4 oc = *(const f32x4*)&osc_i[bb * 128 + f0 + c4 * 4];
            f32x4 oh = *(const f32x4*)&osh_i[bb * 128 + f0 + c4 * 4];
            f32x4 o = v * oc + oh;
            *(f32x4*)&out[((size_t)bb * 192 + tt * 24 + col) * 128 + f0 + c4 * 4] = o;
        }
    }
}

extern "C" void kernel_launch(void* const* d_in, const int* in_sizes, int n_in,
                              void* d_out, int out_size, void* d_ws, size_t ws_size,
                              hipStream_t stream) {
    (void)in_sizes; (void)n_in; (void)out_size; (void)ws_size;
    const float* x          = (const float*)d_in[0];
    const float* revin_w    = (const float*)d_in[1];
    const float* revin_b    = (const float*)d_in[2];
    const float* W_enc      = (const float*)d_in[3];
    const float* b_enc      = (const float*)d_in[4];
    const float* W_vel      = (const float*)d_in[5];
    const float* b_vel      = (const float*)d_in[6];
    const float* step_sizes = (const float*)d_in[7];
    const float* W1         = (const float*)d_in[8];
    const float* b1         = (const float*)d_in[9];
    const float* W2         = (const float*)d_in[10];
    const float* b2         = (const float*)d_in[11];
    float* out = (float*)d_out;

    float* wsf   = (float*)d_ws;
    float* sc    = wsf;                          // 16384
    float* sh    = sc + 16384;
    float* osc   = sh + 16384;
    float* osh   = osc + 16384;
    float* z0    = osh + 16384;                  // 16384*128
    float* vinit = z0 + (size_t)16384 * 128;
    float* mx    = vinit + (size_t)16384 * 128;  // 16384*128
    float* cvec  = mx + (size_t)16384 * 128;     // 128
    float* scp   = cvec + 128;                   // 64 (pad)
    ushort* W1t  = (ushort*)(scp + 64);          // 32768
    ushort* W2tp = W1t + 32768;                  // 8192
    ushort* Wvh  = W2tp + 8192;                  // 16384
    ushort* Wvl  = Wvh + 16384;                  // 16384
    ushort* Weth = Wvl + 16384;                  // 4096
    ushort* Wetl = Weth + 4096;                  // 4096
    ushort* ub   = Wetl + 4096;                  // 229376*128 bf16 (58.7MB)
    ushort* tanb = ub;                           // aliased: ub dead before k_future writes

    k_prep<<<dim3(241), dim3(256), 0, stream>>>(W1, W2, W_vel, b_vel, W_enc,
                                                W1t, W2tp, Wvh, Wvl, Weth, Wetl, cvec, scp);
    k_stats<<<dim3(512), dim3(256), 0, stream>>>(x, revin_w, revin_b, sc, sh, osc, osh);
    k_u<<<dim3(1792), dim3(256), 0, stream>>>(x, sc, sh, Weth, Wetl, b_enc, ub);
    k_encode<<<dim3(512), dim3(256), 0, stream>>>(ub, z0, vinit);
    k_mv<<<dim3(512), dim3(256), 0, stream>>>(vinit, Wvh, Wvl, mx);
    k_future<<<dim3(4096), dim3(256), 0, stream>>>(z0, vinit, mx, cvec, scp, step_sizes, tanb);
    k_head<<<dim3(2048), dim3(256), 0, stream>>>(tanb, W1t, b1, W2tp, b2, osc, osh, out);
}

// Round 12
// 116.415 us; speedup vs baseline: 1.0802x; 1.0802x over previous
//
#include <hip/hip_runtime.h>
#include <hip/hip_bf16.h>

#define EPSF 1e-15f
#define MAXNF 0.99999f

typedef __attribute__((ext_vector_type(8))) short short8v;
typedef __attribute__((ext_vector_type(8))) ushort ushort8v;
typedef __attribute__((ext_vector_type(4))) float f32x4;

__device__ __forceinline__ float wave_sum(float v) {
#pragma unroll
    for (int off = 32; off > 0; off >>= 1) v += __shfl_xor(v, off, 64);
    return v;
}
__device__ __forceinline__ float rcpf(float x) { return __builtin_amdgcn_rcpf(x); }
// x >= 0; series guard avoids (1-e) cancellation at small x (branchy: wave-uniform x)
__device__ __forceinline__ float tanh_g(float x) {
    if (x < 0.03f) return x * (1.f - 0.33333333f * x * x);
    float e = __expf(-2.f * x);
    return (1.f - e) * rcpf(1.f + e);
}
__device__ __forceinline__ float atanh_g(float x) {
    if (x < 0.03f) return x * (1.f + 0.33333333f * x * x);
    return 0.5f * __logf((1.f + x) * rcpf(1.f - x));
}
// branchless variants for lane-divergent inputs
__device__ __forceinline__ float tanh_b(float x) {
    float e = __expf(-2.f * x);
    float tv = (1.f - e) * rcpf(1.f + e);
    float sv = x * (1.f - 0.33333333f * x * x);
    return (x < 0.03f) ? sv : tv;
}
__device__ __forceinline__ float atanh_b(float x) {
    float lv = 0.5f * __logf((1.f + x) * rcpf(1.f - x));
    float sv = x * (1.f + 0.33333333f * x * x);
    return (x < 0.03f) ? sv : lv;
}
__device__ __forceinline__ ushort f2bf(float f) {
    uint32_t u = __float_as_uint(f);
    uint32_t r = (u + 0x7fffu + ((u >> 16) & 1u)) >> 16;
    return (ushort)r;
}
__device__ __forceinline__ float bf2f(ushort u) { return __uint_as_float(((uint32_t)u) << 16); }

// ---------------- K0: prep — W1^T/W2^T bf16, W_vel hi/lo, W_enc^T hi/lo, c = expmap0(b_vel) ----------------
__global__ __launch_bounds__(256) void k_prep(
    const float* __restrict__ W1, const float* __restrict__ W2,
    const float* __restrict__ W_vel, const float* __restrict__ b_vel,
    const float* __restrict__ W_enc,
    ushort* __restrict__ W1t, ushort* __restrict__ W2tp,
    ushort* __restrict__ Wvh, ushort* __restrict__ Wvl,
    ushort* __restrict__ Weth, ushort* __restrict__ Wetl,
    float* __restrict__ cvec, float* __restrict__ scp) {
    int bid = blockIdx.x, tid = threadIdx.x;
    if (bid == 0) {
        __shared__ float red[4];
        float v = (tid < 128) ? b_vel[tid] : 0.f;
        float p = wave_sum(v * v);
        if ((tid & 63) == 0) red[tid >> 6] = p;
        __syncthreads();
        float ssq = red[0] + red[1] + red[2] + red[3];
        float nn = sqrtf(fmaxf(ssq, EPSF));
        float th = tanhf(nn);
        if (tid < 128) cvec[tid] = th / nn * v;
        if (tid == 0) scp[0] = th * th;
    } else if (bid <= 128) {
        int idx = (bid - 1) * 256 + tid;      // n*128 + k
        int n = idx >> 7, k = idx & 127;
        W1t[idx] = f2bf(W1[k * 256 + n]);
    } else if (bid <= 160) {
        int idx = (bid - 129) * 256 + tid;    // s*256 + j  (s padded to 32)
        int s = idx >> 8, j = idx & 255;
        W2tp[idx] = (s < 24) ? f2bf(W2[j * 24 + s]) : (ushort)0;
    } else if (bid <= 224) {
        int idx = (bid - 161) * 256 + tid;    // j*128 + k
        float wv = W_vel[idx];
        ushort h = f2bf(wv);
        Wvh[idx] = h;
        Wvl[idx] = f2bf(wv - bf2f(h));
    } else {
        int idx = (bid - 225) * 256 + tid;    // d*32 + s (s padded to 32)
        int d = idx >> 5, s = idx & 31;
        float wv = (s < 24) ? W_enc[s * 128 + d] : 0.f;
        ushort h = f2bf(wv);
        Weth[idx] = h;
        Wetl[idx] = f2bf(wv - bf2f(h));
    }
}

// ---------------- K1: RevIN stats -> norm + denorm coeffs (32 f per block) ----------------
__global__ __launch_bounds__(256) void k_stats(
    const float* __restrict__ x, const float* __restrict__ revin_w, const float* __restrict__ revin_b,
    float* __restrict__ sc_o, float* __restrict__ sh_o,
    float* __restrict__ osc_o, float* __restrict__ osh_o) {
    __shared__ float ps[8][32], ps2[8][32];
    int b = blockIdx.x >> 2, fg = blockIdx.x & 3, tid = threadIdx.x;
    int f = fg * 32 + (tid & 31), sl = tid >> 5;   // 8 L-slices of 42
    const float* xp = x + ((size_t)b * 336 + sl * 42) * 128 + f;
    float s = 0.f, s2 = 0.f;
    for (int l = 0; l < 42; ++l) { float v = xp[(size_t)l * 128]; s += v; s2 += v * v; }
    ps[sl][tid & 31] = s; ps2[sl][tid & 31] = s2;
    __syncthreads();
    if (tid < 32) {
        float S = 0.f, S2 = 0.f;
#pragma unroll
        for (int h = 0; h < 8; ++h) { S += ps[h][tid]; S2 += ps2[h][tid]; }
        float m = S * (1.f / 336.f);
        float var = S2 * (1.f / 336.f) - m * m;
        float sd = sqrtf(var + 1e-5f);
        int ff = fg * 32 + tid;
        int r = b * 128 + ff;
        float rw = revin_w[ff], rb = revin_b[ff];
        float sc = rw * rcpf(sd);
        sc_o[r] = sc;
        sh_o[r] = rb - m * sc;
        float oc = sd * rcpf(rw);
        osc_o[r] = oc;
        osh_o[r] = m - rb * oc;
    }
}

// ---------------- K2: FUSED u-GEMM + hyperbolic recurrence (u lives in LDS, never hits HBM) ----------------
// Block = (b, 32-f slice), grid 512. u_lds[f][n][d]: f-stride 2056 us (4112B), d XOR-swizzled by n.
__global__ __launch_bounds__(256) void k_uenc(
    const float* __restrict__ x, const float* __restrict__ sc_i, const float* __restrict__ sh_i,
    const ushort* __restrict__ Weth, const ushort* __restrict__ Wetl,
    const float* __restrict__ b_enc,
    float* __restrict__ z0_o, float* __restrict__ vinit_o) {
    __shared__ ushort u_lds[32 * 2056];      // 131.6 KB
    __shared__ ushort xs[2][32][88];         // [buf][f][0..31 hi | 48..79 lo], 11.3 KB
    __shared__ float scs[32], shs[32];
    __shared__ float gram[32][29];
    __shared__ float coef[32][17];
    int bidx = blockIdx.x;
    int b = bidx >> 2, f0 = (bidx & 3) * 32;
    int tid = threadIdx.x, wid = tid >> 6, lane = tid & 63;
    int lrow = lane & 15, lk = lane >> 4;

    // init: zero xs (K-padding) + u rows n=14,15 (Gram garbage guard); stage norm coeffs
    for (int e = tid; e < 5632; e += 256) ((ushort*)xs)[e] = 0;
    for (int e = tid; e < 32 * 256; e += 256) u_lds[(e >> 8) * 2056 + 14 * 128 + (e & 255)] = 0;
    if (tid < 32) { scs[tid] = sc_i[b * 128 + f0 + tid]; shs[tid] = sh_i[b * 128 + f0 + tid]; }

    // W_enc^T B-frags: wave owns d in [wid*32, wid*32+32)
    short8v Bh[2], Bl[2]; float be[2];
#pragma unroll
    for (int dt = 0; dt < 2; ++dt) {
        int d = wid * 32 + dt * 16 + lrow;
        Bh[dt] = *(const short8v*)(Weth + d * 32 + lk * 8);
        Bl[dt] = *(const short8v*)(Wetl + d * 32 + lk * 8);
        be[dt] = b_enc[d];
    }
    __syncthreads();

    int fi = tid & 31;
    float scf = scs[fi], shf = shs[fi];
    // prologue: stage n=0
    {
#pragma unroll
        for (int k = 0; k < 3; ++k) {
            int s = (tid + k * 256) >> 5;
            float v = x[((size_t)(b * 336 + s)) * 128 + f0 + fi] * scf + shf;
            ushort h = f2bf(v);
            xs[0][fi][s] = h;
            xs[0][fi][48 + s] = f2bf(v - bf2f(h));
        }
    }
    __syncthreads();

    for (int n = 0; n < 14; ++n) {
        int buf = n & 1;
        // issue next-segment loads into regs (overlap with compute)
        float vst[3];
        if (n + 1 < 14) {
#pragma unroll
            for (int k = 0; k < 3; ++k) {
                int s = (tid + k * 256) >> 5;
                vst[k] = x[((size_t)(b * 336 + (n + 1) * 24 + s)) * 128 + f0 + fi] * scf + shf;
            }
        }
        // GEMM: u[32f][128d] for this n (hi/lo 3-MFMA ~ fp32)
        int nx = (n & 7) << 4;
#pragma unroll
        for (int ft = 0; ft < 2; ++ft) {
            int fr = ft * 16 + lrow;
            short8v Ah = *(const short8v*)&xs[buf][fr][lk * 8];
            short8v Al = *(const short8v*)&xs[buf][fr][48 + lk * 8];
#pragma unroll
            for (int dt = 0; dt < 2; ++dt) {
                f32x4 acc = (f32x4)(0.f);
                acc = __builtin_amdgcn_mfma_f32_16x16x32_bf16(Ah, Bh[dt], acc, 0, 0, 0);
                acc = __builtin_amdgcn_mfma_f32_16x16x32_bf16(Ah, Bl[dt], acc, 0, 0, 0);
                acc = __builtin_amdgcn_mfma_f32_16x16x32_bf16(Al, Bh[dt], acc, 0, 0, 0);
                int dx = (wid * 32 + dt * 16 + lrow) ^ nx;
#pragma unroll
                for (int j = 0; j < 4; ++j) {
                    int f = ft * 16 + lk * 4 + j;
                    u_lds[f * 2056 + n * 128 + dx] = f2bf(acc[j] + be[dt]);
                }
            }
        }
        // write staged n+1
        if (n + 1 < 14) {
#pragma unroll
            for (int k = 0; k < 3; ++k) {
                int s = (tid + k * 256) >> 5;
                ushort h = f2bf(vst[k]);
                xs[buf ^ 1][fi][s] = h;
                xs[buf ^ 1][fi][48 + s] = f2bf(vst[k] - bf2f(h));
            }
        }
        __syncthreads();
    }

    // Phase A: Gram U·U^T per f-row via MFMA (frag rows = n, K = d)
    for (int i = 0; i < 8; i += 2) {
        int rl0 = wid * 8 + i, rl1 = rl0 + 1;
        int roff0 = rl0 * 2056 + lrow * 128;
        int roff1 = roff0 + 2056;
        short8v a0[4], a1[4];
#pragma unroll
        for (int kk = 0; kk < 4; ++kk) {
            int coff = (kk * 32 + lk * 8) ^ ((lrow & 7) << 4);
            a0[kk] = *(const short8v*)&u_lds[roff0 + coff];
            a1[kk] = *(const short8v*)&u_lds[roff1 + coff];
        }
        f32x4 g0 = (f32x4)(0.f), g1 = (f32x4)(0.f);
#pragma unroll
        for (int kk = 0; kk < 4; ++kk) {
            g0 = __builtin_amdgcn_mfma_f32_16x16x32_bf16(a0[kk], a0[kk], g0, 0, 0, 0);
            g1 = __builtin_amdgcn_mfma_f32_16x16x32_bf16(a1[kk], a1[kk], g1, 0, 0, 0);
        }
#pragma unroll
        for (int j = 0; j < 4; ++j) {
            int crow = lk * 4 + j, ccol = lrow;
            if (crow == ccol && crow < 14) { gram[rl0][crow] = g0[j]; gram[rl1][crow] = g1[j]; }
            if (crow + 1 == ccol && ccol < 14) { gram[rl0][14 + ccol] = g0[j]; gram[rl1][14 + ccol] = g1[j]; }
        }
    }
    __syncthreads();

    // Phase B: 32 lanes, 1 row each — scalar recurrence -> linear coefficients
    if (tid < 32) {
        float wsum = 0.f;
        { float p = 1.f; for (int k = 0; k < 13; ++k) { wsum += p; p *= 0.9f; } }
        float wi; { float p = 1.f; for (int k = 0; k < 12; ++k) p *= 0.9f; wi = p / (wsum * 13.f); }
        float c[14];
#pragma unroll
        for (int m = 0; m < 14; ++m) c[m] = 0.f;
        float sczp = 0.f, szp = 0.f;
#pragma unroll
        for (int n = 0; n < 14; ++n) {
            float ssq = gram[tid][n];
            float nn = sqrtf(fmaxf(ssq, EPSF));
            float th = tanh_g(nn);
            float scz, sz;
            if (th > MAXNF) { scz = MAXNF * rcpf(nn); sz = MAXNF * MAXNF; }
            else            { scz = th * rcpf(nn);    sz = th * th; }
            if (n > 0) {
                float dotup = gram[tid][14 + n];
                float xyp = sczp * scz * dotup;
                float t2 = 1.f - 2.f * xyp;
                float den = fmaxf(t2 + szp * sz, EPSF);
                float rden = rcpf(den);
                float a1 = t2 + sz, a2 = 1.f - szp;
                float usq = (a1 * a1 * szp - 2.f * a1 * a2 * xyp + a2 * a2 * sz) * (rden * rden);
                float un = sqrtf(fmaxf(usq, EPSF));
                float art = atanh_g(fminf(un, 1.f - 1e-7f));
                float fac = fmaxf(a2, EPSF) * art * rcpf(un) * rden * wi;
                c[n - 1] += -fac * a1 * sczp;
                c[n]     +=  fac * a2 * scz;
                wi *= (1.f / 0.9f);
            }
            sczp = scz; szp = sz;
        }
#pragma unroll
        for (int m = 0; m < 14; ++m) coef[tid][m] = c[m];
        coef[tid][14] = sczp;
    }
    __syncthreads();

    // Phase C: vinit = sum_n c_n u_n ; z0 = scz_last * u_13  (2 d per lane, from LDS)
    for (int i = 0; i < 8; ++i) {
        int rl = wid * 8 + i;
        float cc[15];
#pragma unroll
        for (int m = 0; m < 15; ++m) cc[m] = coef[rl][m];
        float v0 = 0.f, v1 = 0.f, za = 0.f, zb = 0.f;
#pragma unroll
        for (int n = 0; n < 14; ++n) {
            uint u = *(const uint*)&u_lds[rl * 2056 + n * 128 + ((lane * 2) ^ ((n & 7) << 4))];
            float x0 = __uint_as_float(u << 16);
            float x1 = __uint_as_float(u & 0xffff0000u);
            v0 += cc[n] * x0; v1 += cc[n] * x1;
            if (n == 13) { za = cc[14] * x0; zb = cc[14] * x1; }
        }
        size_t ob = (size_t)(b * 128 + f0 + rl) * 128 + lane * 2;
        *(float2*)&vinit_o[ob] = make_float2(v0, v1);
        *(float2*)&z0_o[ob] = make_float2(za, zb);
    }
}

// ---------------- K4: mx = vinit @ W_vel^T via MFMA (bf16 hi/lo split ~ fp32) ----------------
__global__ __launch_bounds__(256) void k_mv(
    const float* __restrict__ vinit,
    const ushort* __restrict__ Wvh, const ushort* __restrict__ Wvl,
    float* __restrict__ mx_o) {
    int wid = threadIdx.x >> 6, lane = threadIdx.x & 63;
    int lrow = lane & 15, lk = lane >> 4;
    int r0 = blockIdx.x * 32;
    short8v Bh[2][4], Bl[2][4];
#pragma unroll
    for (int nt = 0; nt < 2; ++nt) {
        const ushort* wph = Wvh + (size_t)((wid * 2 + nt) * 16 + lrow) * 128 + lk * 8;
        const ushort* wpl = Wvl + (size_t)((wid * 2 + nt) * 16 + lrow) * 128 + lk * 8;
#pragma unroll
        for (int kk = 0; kk < 4; ++kk) {
            Bh[nt][kk] = *(const short8v*)(wph + kk * 32);
            Bl[nt][kk] = *(const short8v*)(wpl + kk * 32);
        }
    }
    f32x4 acc[2][2];
#pragma unroll
    for (int rg = 0; rg < 2; ++rg) { acc[rg][0] = (f32x4)(0.f); acc[rg][1] = (f32x4)(0.f); }
#pragma unroll
    for (int rg = 0; rg < 2; ++rg) {
#pragma unroll
        for (int kk = 0; kk < 4; ++kk) {
            const float* ap = vinit + (size_t)(r0 + rg * 16 + lrow) * 128 + kk * 32 + lk * 8;
            f32x4 a0 = *(const f32x4*)ap;
            f32x4 a1 = *(const f32x4*)(ap + 4);
            short8v Ah, Al;
#pragma unroll
            for (int i = 0; i < 8; ++i) {
                float xv = (i < 4) ? a0[i] : a1[i - 4];
                ushort h = f2bf(xv);
                Ah[i] = (short)h;
                Al[i] = (short)f2bf(xv - bf2f(h));
            }
#pragma unroll
            for (int nt = 0; nt < 2; ++nt) {
                acc[rg][nt] = __builtin_amdgcn_mfma_f32_16x16x32_bf16(Ah, Bh[nt][kk], acc[rg][nt], 0, 0, 0);
                acc[rg][nt] = __builtin_amdgcn_mfma_f32_16x16x32_bf16(Ah, Bl[nt][kk], acc[rg][nt], 0, 0, 0);
                acc[rg][nt] = __builtin_amdgcn_mfma_f32_16x16x32_bf16(Al, Bh[nt][kk], acc[rg][nt], 0, 0, 0);
            }
        }
    }
#pragma unroll
    for (int rg = 0; rg < 2; ++rg)
#pragma unroll
        for (int nt = 0; nt < 2; ++nt)
#pragma unroll
            for (int j = 0; j < 4; ++j)
                mx_o[(size_t)(r0 + rg * 16 + lk * 4 + j) * 128 + (wid * 2 + nt) * 16 + lrow] = acc[rg][nt][j];
}

// ---------------- K5: v0t tail + futures -> tan (bf16); f-major layout R=b*1024+t*128+f ----------------
__global__ __launch_bounds__(256) void k_future(
    const float* __restrict__ z0_i, const float* __restrict__ vinit, const float* __restrict__ mx_i,
    const float* __restrict__ cvec, const float* __restrict__ scp,
    const float* __restrict__ step_sizes, ushort* __restrict__ tanb) {
    int wid = threadIdx.x >> 6, lane = threadIdx.x & 63;
    int r = blockIdx.x * 4 + wid;
    size_t base = (size_t)r * 128 + lane * 2;
    float2 vi = *(const float2*)&vinit[base];
    float2 mx = *(const float2*)&mx_i[base];
    float2 z0 = *(const float2*)&z0_i[base];
    float2 cv = *(const float2*)&cvec[lane * 2];
    float scc = scp[0];
    float xn2  = wave_sum(vi.x * vi.x + vi.y * vi.y);
    float mxn2 = wave_sum(mx.x * mx.x + mx.y * mx.y);
    float mxc  = wave_sum(mx.x * cv.x + mx.y * cv.y);
    float z0mx = wave_sum(z0.x * mx.x + z0.y * mx.y);
    float z0c  = wave_sum(z0.x * cv.x + z0.y * cv.y);
    float x2   = wave_sum(z0.x * z0.x + z0.y * z0.y);
    float xn = sqrtf(fmaxf(xn2, EPSF));
    float mxn = sqrtf(fmaxf(mxn2, EPSF));
    float artx = atanh_g(fminf(xn, 1.f - 1e-7f));
    float tm = tanh_g(mxn * rcpf(xn) * artx);
    float scm = tm * rcpf(mxn);
    float sm = tm * tm;
    float xy2 = scm * mxc;
    float den2 = fmaxf(1.f + 2.f * xy2 + sm * scc, EPSF);
    float rd2 = rcpf(den2);
    float A2 = (1.f + 2.f * xy2 + scc) * scm * rd2;
    float B2 = (1.f - sm) * rd2;
    float v0n2 = A2 * A2 * mxn2 + 2.f * A2 * B2 * mxc + B2 * B2 * scc;
    float nv0 = sqrtf(fmaxf(v0n2, EPSF));
    if (nv0 > MAXNF) { float pf = MAXNF * rcpf(nv0); A2 *= pf; B2 *= pf; nv0 = MAXNF; }
    v0n2 = nv0 * nv0;
    float inv_nv0 = rcpf(nv0);
    float zdv = A2 * z0mx + B2 * z0c;
    float v00 = A2 * mx.x + B2 * cv.x, v01 = A2 * mx.y + B2 * cv.y;
    float il = rcpf(fmaxf(1.f - x2, EPSF));
    float step = rcpf(1.f + __expf(-step_sizes[0]));
    float tl = (float)((lane & 7) + 1);
    float nt_ = step * tl * nv0;
    float th = tanh_b(nt_ * il);
    float xy = th * inv_nv0 * zdv;
    float y2 = th * th;
    float den = fmaxf(1.f + 2.f * xy + x2 * y2, EPSF);
    float rd = rcpf(den);
    float A = (1.f + 2.f * xy + y2) * rd;
    float B = (1.f - x2) * th * inv_nv0 * rd;
    float rsq = A * A * x2 + 2.f * A * B * zdv + B * B * v0n2;
    float nr = sqrtf(fmaxf(rsq, EPSF));
    float pf2 = (nr > MAXNF) ? MAXNF * rcpf(nr) : 1.f;
    A *= pf2; B *= pf2; nr = fminf(nr, MAXNF);
    float art = atanh_b(fminf(nr, 1.f - 1e-7f));
    float tf = art * rcpf(nr);
    float FA = tf * A, FB = tf * B;
    uint* t32 = (uint*)tanb;
    int bb = r >> 7, f = r & 127;
#pragma unroll
    for (int t = 0; t < 8; ++t) {
        float FAt = __shfl(FA, t);
        float FBt = __shfl(FB, t);
        uint pk = (uint)f2bf(FAt * z0.x + FBt * v00) | ((uint)f2bf(FAt * z0.y + FBt * v01) << 16);
        t32[((size_t)(bb * 1024 + t * 128 + f)) * 64 + lane] = pk;
    }
}

// ---------------- K6: head — N-split waves, B-resident, 4-tile loop, coalesced f-major epilogue ----------------
// grid 512 x 256. Tile = 64 rows = one (b, t, f-half). Wave w owns GEMM1 cols [w*64,w*64+64).
__global__ __launch_bounds__(256, 2) void k_head(
    const ushort* __restrict__ tanb, const ushort* __restrict__ W1t, const float* __restrict__ b1,
    const ushort* __restrict__ W2tp, const float* __restrict__ b2,
    const float* __restrict__ osc_i, const float* __restrict__ osh_i,
    float* __restrict__ out) {
    __shared__ __align__(16) ushort hs[64][264];   // 33.8 KB; front 6.5 KB reused as ep[24][68] floats
    int tid = threadIdx.x;
    int wid = tid >> 6, lane = tid & 63;
    int lrow = lane & 15, lk = lane >> 4;

    // persistent GEMM1 B-frags (loaded once per 4 tiles)
    short8v Bw[4][4];
#pragma unroll
    for (int nt = 0; nt < 4; ++nt) {
        const ushort* wp = W1t + (size_t)((wid * 4 + nt) * 16 + lrow) * 128 + lk * 8;
#pragma unroll
        for (int kk = 0; kk < 4; ++kk) Bw[nt][kk] = *(const short8v*)(wp + kk * 32);
    }
    float b1v[4];
#pragma unroll
    for (int nt = 0; nt < 4; ++nt) b1v[nt] = b1[(wid * 4 + nt) * 16 + lrow];
    float b2a = (lrow < 24) ? b2[lrow] : 0.f;
    float b2bv = (lrow < 8) ? b2[16 + lrow] : 0.f;

    int tile0 = blockIdx.x * 4;
    short8v A[4][4];
    {
        const ushort* tp = tanb + ((size_t)tile0 * 64 + lrow) * 128 + lk * 8;
#pragma unroll
        for (int rg = 0; rg < 4; ++rg)
#pragma unroll
            for (int kk = 0; kk < 4; ++kk)
                A[rg][kk] = *(const short8v*)(tp + (size_t)rg * 2048 + kk * 32);
    }
#pragma unroll
    for (int it = 0; it < 4; ++it) {
        int tile = tile0 + it;
        f32x4 acc[4][4];
#pragma unroll
        for (int rg = 0; rg < 4; ++rg)
#pragma unroll
            for (int nt = 0; nt < 4; ++nt) acc[rg][nt] = (f32x4)(0.f);
#pragma unroll
        for (int kk = 0; kk < 4; ++kk)
#pragma unroll
            for (int rg = 0; rg < 4; ++rg)
#pragma unroll
                for (int nt = 0; nt < 4; ++nt)
                    acc[rg][nt] = __builtin_amdgcn_mfma_f32_16x16x32_bf16(A[rg][kk], Bw[nt][kk], acc[rg][nt], 0, 0, 0);
        // prefetch next tile's A; latency hides under LDS + GEMM2 + epilogue
        if (it + 1 < 4) {
            const ushort* tp = tanb + ((size_t)(tile + 1) * 64 + lrow) * 128 + lk * 8;
#pragma unroll
            for (int rg = 0; rg < 4; ++rg)
#pragma unroll
                for (int kk = 0; kk < 4; ++kk)
                    A[rg][kk] = *(const short8v*)(tp + (size_t)rg * 2048 + kk * 32);
        }
        __syncthreads();   // protect previous iter's hs/ep reads before overwrite (no-op on it 0)
#pragma unroll
        for (int rg = 0; rg < 4; ++rg)
#pragma unroll
            for (int nt = 0; nt < 4; ++nt)
#pragma unroll
                for (int j = 0; j < 4; ++j)
                    hs[rg * 16 + lk * 4 + j][(wid * 4 + nt) * 16 + lrow] =
                        f2bf(fmaxf(acc[rg][nt][j] + b1v[nt], 0.f));
        __syncthreads();
        // GEMM2: wave computes its 16 rows over full K=256
        f32x4 acc2[2];
        acc2[0] = (f32x4)(0.f); acc2[1] = (f32x4)(0.f);
#pragma unroll
        for (int kk2 = 0; kk2 < 8; ++kk2) {
            short8v Ah = *(const short8v*)&hs[wid * 16 + lrow][kk2 * 32 + lk * 8];
#pragma unroll
            for (int nt2 = 0; nt2 < 2; ++nt2) {
                short8v Bv = *(const short8v*)(W2tp + (size_t)(nt2 * 16 + lrow) * 256 + kk2 * 32 + lk * 8);
                acc2[nt2] = __builtin_amdgcn_mfma_f32_16x16x32_bf16(Ah, Bv, acc2[nt2], 0, 0, 0);
            }
        }
        __syncthreads();   // all hs reads done; safe to reuse as ep
        float* ep = (float*)&hs[0][0];   // [24][68]
#pragma unroll
        for (int nt2 = 0; nt2 < 2; ++nt2) {
            int col = nt2 * 16 + lrow;
            if (col < 24) {
                float bb2 = (nt2 == 0) ? b2a : b2bv;
#pragma unroll
                for (int j = 0; j < 4; ++j)
                    ep[col * 68 + wid * 16 + lk * 4 + j] = acc2[nt2][j] + bb2;
            }
        }
        __syncthreads();
        // coalesced store: 384 float4; per (b,t,col) a 256B contiguous f-run
        int bb = tile >> 4, rem = tile & 15, tt = rem >> 1, f0 = (rem & 1) << 6;
#pragma unroll
        for (int pass = 0; pass < 2; ++pass) {
            int id = pass * 256 + tid;
            if (id < 384) {
                int col = id >> 4, c4 = id & 15;
                f32x4 v = *(f32x4*)&ep[col * 68 + c4 * 4];
                f32x4 oc = *(const f32x4*)&osc_i[bb * 128 + f0 + c4 * 4];
                f32x4 oh = *(const f32x4*)&osh_i[bb * 128 + f0 + c4 * 4];
                f32x4 o = v * oc + oh;
                *(f32x4*)&out[((size_t)bb * 192 + tt * 24 + col) * 128 + f0 + c4 * 4] = o;
            }
        }
    }
}

extern "C" void kernel_launch(void* const* d_in, const int* in_sizes, int n_in,
                              void* d_out, int out_size, void* d_ws, size_t ws_size,
                              hipStream_t stream) {
    (void)in_sizes; (void)n_in; (void)out_size; (void)ws_size;
    const float* x          = (const float*)d_in[0];
    const float* revin_w    = (const float*)d_in[1];
    const float* revin_b    = (const float*)d_in[2];
    const float* W_enc      = (const float*)d_in[3];
    const float* b_enc      = (const float*)d_in[4];
    const float* W_vel      = (const float*)d_in[5];
    const float* b_vel      = (const float*)d_in[6];
    const float* step_sizes = (const float*)d_in[7];
    const float* W1         = (const float*)d_in[8];
    const float* b1         = (const float*)d_in[9];
    const float* W2         = (const float*)d_in[10];
    const float* b2         = (const float*)d_in[11];
    float* out = (float*)d_out;

    float* wsf   = (float*)d_ws;
    float* sc    = wsf;                          // 16384
    float* sh    = sc + 16384;
    float* osc   = sh + 16384;
    float* osh   = osc + 16384;
    float* z0    = osh + 16384;                  // 16384*128
    float* vinit = z0 + (size_t)16384 * 128;
    float* mx    = vinit + (size_t)16384 * 128;  // 16384*128
    float* cvec  = mx + (size_t)16384 * 128;     // 128
    float* scp   = cvec + 128;                   // 64 (pad)
    ushort* W1t  = (ushort*)(scp + 64);          // 32768
    ushort* W2tp = W1t + 32768;                  // 8192
    ushort* Wvh  = W2tp + 8192;                  // 16384
    ushort* Wvl  = Wvh + 16384;                  // 16384
    ushort* Weth = Wvl + 16384;                  // 4096
    ushort* Wetl = Weth + 4096;                  // 4096
    ushort* tanb = Wetl + 4096;                  // 131072*128 bf16 (33.5MB)

    k_prep<<<dim3(241), dim3(256), 0, stream>>>(W1, W2, W_vel, b_vel, W_enc,
                                                W1t, W2tp, Wvh, Wvl, Weth, Wetl, cvec, scp);
    k_stats<<<dim3(512), dim3(256), 0, stream>>>(x, revin_w, revin_b, sc, sh, osc, osh);
    k_uenc<<<dim3(512), dim3(256), 0, stream>>>(x, sc, sh, Weth, Wetl, b_enc, z0, vinit);
    k_mv<<<dim3(512), dim3(256), 0, stream>>>(vinit, Wvh, Wvl, mx);
    k_future<<<dim3(4096), dim3(256), 0, stream>>>(z0, vinit, mx, cvec, scp, step_sizes, tanb);
    k_head<<<dim3(512), dim3(256), 0, stream>>>(tanb, W1t, b1, W2tp, b2, osc, osh, out);
}